// Round 9
// baseline (319.586 us; speedup 1.0000x reference)
//
#include <hip/hip_runtime.h>
#include <hip/hip_cooperative_groups.h>

namespace cg = cooperative_groups;

#define N_NODES 50000
#define N_EDGES 800000
#define IN_SIZE 128
#define OUT_SIZE 64
#define BIN_CAP 64   // Poisson(16) => P(>=64) ~ 2e-18

#define BM 128
#define NGEMM ((N_NODES + BM - 1) / BM)      // 391 gemm tiles
#define NCH   (N_EDGES / 4)                  // 200000 int4 edge-groups
#define NBIN  ((NCH + 255) / 256)            // 782 bin chunks
#define RPQ   ((N_NODES + 7) / 8)            // 6250 rows per XCD slice

typedef __attribute__((ext_vector_type(8))) short short8v;  // 8 bf16 (4 VGPRs)
typedef __attribute__((ext_vector_type(4))) float f32x4;

__device__ __forceinline__ unsigned short f2bf(float f) {    // RTNE fp32->bf16
    unsigned u = __float_as_uint(f);
    return (unsigned short)((u + 0x7fffu + ((u >> 16) & 1u)) >> 16);
}
__device__ __forceinline__ unsigned pk2(float a, float b) {  // pack 2 bf16
    return (unsigned)f2bf(a) | ((unsigned)f2bf(b) << 16);
}

// =========================================================================
// Cooperative kernel:
//  phase0: zero cnt, read XCC_ID
//  phase1a: MFMA bf16 gemm tiles off shared queue q[0]
//  phase1b: XCD-local edge binning (queues q[1..8], own-XCD first, steal after)
//  phase2: per-row gather-reduce (+bias)
// NO min-waves cap (R7: capping spills the accumulators -> 6x regression).
// =========================================================================
__global__ __launch_bounds__(256) void gcn_coop(
        const float* __restrict__ x, const float* __restrict__ w,
        const int* __restrict__ rows, const int* __restrict__ cols,
        const float* __restrict__ vals, const float* __restrict__ bias,
        float* __restrict__ support, int* __restrict__ cnt,
        int2* __restrict__ pay, int* __restrict__ q,
        float* __restrict__ out) {
    __shared__ int4 xs4[2048];     // 32 KB: bf16 x-tile, [128 rows][256 B] swizzled
    __shared__ int  wt4[4096];     // 16 KB: bf16 w^T,   [64 cols][256 B] swizzled
    __shared__ int task_s;
    __shared__ unsigned xcd_s;
    char* xb = (char*)xs4;
    char* wb = (char*)wt4;
    const int tid = threadIdx.x;
    cg::grid_group grid = cg::this_grid();

    // ---------------- phase 0 ----------------
    for (int i = blockIdx.x * 256 + tid; i < N_NODES; i += gridDim.x * 256)
        cnt[i] = 0;
    if (blockIdx.x == 0 && tid < 9) q[tid] = 0;
    if (tid == 0) {
        unsigned v = 0;
        asm volatile("s_getreg_b32 %0, hwreg(20, 0, 4)" : "=s"(v)); // XCC_ID
        xcd_s = v & 7u;
    }
    grid.sync();
    const unsigned myq = xcd_s;

    // ---------------- phase 1a: MFMA gemm tiles ----------------
    bool wloaded = false;
    for (;;) {
        if (tid == 0) task_s = atomicAdd(&q[0], 1);
        __syncthreads();
        const int t = task_s;
        __syncthreads();
        if (t >= NGEMM) break;
        const int row0 = t * BM;

        // stage x tile -> bf16 LDS, swizzle: byte ^= (row&7)<<4
        #pragma unroll
        for (int i = 0; i < 8; ++i) {
            const int s   = tid + 256 * i;    // s < 2048 (row, 16B-slot)
            const int row = s >> 4;
            const int sl  = s & 15;
            int r = row0 + row; if (r > N_NODES - 1) r = N_NODES - 1;
            const float4* xp = (const float4*)(x + (long)r * IN_SIZE + sl * 8);
            const float4 f0 = xp[0], f1 = xp[1];
            int4 pk;
            pk.x = pk2(f0.x, f0.y); pk.y = pk2(f0.z, f0.w);
            pk.z = pk2(f1.x, f1.y); pk.w = pk2(f1.z, f1.w);
            *(int4*)(xb + row * 256 + ((sl * 16) ^ ((row & 7) << 4))) = pk;
        }
        if (!wloaded) {   // stage w^T once per block (same swizzle on col)
            wloaded = true;
            #pragma unroll
            for (int i = 0; i < 4; ++i) {
                const int f  = tid + 256 * i;          // f < 1024
                const int kp = f >> 4;                 // k-pair 0..63
                const int c0 = (f & 15) << 2;
                const float4 w0 = *(const float4*)(w + (2 * kp) * OUT_SIZE + c0);
                const float4 w1 = *(const float4*)(w + (2 * kp + 1) * OUT_SIZE + c0);
                const float a0[4] = {w0.x, w0.y, w0.z, w0.w};
                const float a1[4] = {w1.x, w1.y, w1.z, w1.w};
                #pragma unroll
                for (int j = 0; j < 4; ++j) {
                    const int c = c0 + j;
                    *(unsigned*)(wb + c * 256 + ((kp * 4) ^ ((c & 7) << 4))) =
                        pk2(a0[j], a1[j]);
                }
            }
        }
        __syncthreads();

        // compute: wave wv owns rows [wv*32, wv*32+32) x all 64 cols
        const int l   = tid & 63;
        const int wv  = tid >> 6;
        const int rb  = wv * 32;
        const int lm  = l & 15;
        const int swz = (l & 7) << 4;
        f32x4 acc[2][4];
        #pragma unroll
        for (int a16 = 0; a16 < 2; ++a16)
            #pragma unroll
            for (int nb = 0; nb < 4; ++nb)
                acc[a16][nb] = (f32x4){0.f, 0.f, 0.f, 0.f};

        #pragma unroll
        for (int kk = 0; kk < 4; ++kk) {
            const int ko = ((kk << 6) + ((l >> 4) << 4)) ^ swz;
            const short8v a0 = *(const short8v*)(xb + (rb + lm) * 256 + ko);
            const short8v a1 = *(const short8v*)(xb + (rb + 16 + lm) * 256 + ko);
            const short8v b0 = *(const short8v*)(wb + lm * 256 + ko);
            const short8v b1 = *(const short8v*)(wb + (16 + lm) * 256 + ko);
            const short8v b2 = *(const short8v*)(wb + (32 + lm) * 256 + ko);
            const short8v b3 = *(const short8v*)(wb + (48 + lm) * 256 + ko);
            acc[0][0] = __builtin_amdgcn_mfma_f32_16x16x32_bf16(a0, b0, acc[0][0], 0, 0, 0);
            acc[0][1] = __builtin_amdgcn_mfma_f32_16x16x32_bf16(a0, b1, acc[0][1], 0, 0, 0);
            acc[0][2] = __builtin_amdgcn_mfma_f32_16x16x32_bf16(a0, b2, acc[0][2], 0, 0, 0);
            acc[0][3] = __builtin_amdgcn_mfma_f32_16x16x32_bf16(a0, b3, acc[0][3], 0, 0, 0);
            acc[1][0] = __builtin_amdgcn_mfma_f32_16x16x32_bf16(a1, b0, acc[1][0], 0, 0, 0);
            acc[1][1] = __builtin_amdgcn_mfma_f32_16x16x32_bf16(a1, b1, acc[1][1], 0, 0, 0);
            acc[1][2] = __builtin_amdgcn_mfma_f32_16x16x32_bf16(a1, b2, acc[1][2], 0, 0, 0);
            acc[1][3] = __builtin_amdgcn_mfma_f32_16x16x32_bf16(a1, b3, acc[1][3], 0, 0, 0);
        }
        __syncthreads();   // all LDS reads done before next task restages

        // C/D layout (m89-verified): col = lane&15, row = (lane>>4)*4 + reg
        const int rr = (l >> 4) << 2;
        #pragma unroll
        for (int a16 = 0; a16 < 2; ++a16) {
            #pragma unroll
            for (int r4 = 0; r4 < 4; ++r4) {
                const int grow = row0 + rb + a16 * 16 + rr + r4;
                if (grow < N_NODES) {
                    #pragma unroll
                    for (int nb = 0; nb < 4; ++nb)
                        support[(long)grow * OUT_SIZE + nb * 16 + lm] = acc[a16][nb][r4];
                }
            }
        }
    }

    // ---------------- phase 1b: XCD-local binning ----------------
    for (int dq = 0; dq < 8; ++dq) {
        const int qq  = (int)((myq + dq) & 7u);
        const int rlo = qq * RPQ;
        const int rhi = min(rlo + RPQ, N_NODES);
        for (;;) {
            if (tid == 0) task_s = atomicAdd(&q[1 + qq], 1);
            __syncthreads();
            const int c = task_s;
            __syncthreads();
            if (c >= NBIN) break;
            const int i = c * 256 + tid;
            if (i < NCH) {
                const int4   r4 = ((const int4*)rows)[i];
                const int4   c4 = ((const int4*)cols)[i];
                const float4 v4 = ((const float4*)vals)[i];
                if (r4.x >= rlo && r4.x < rhi) { int s = atomicAdd(&cnt[r4.x], 1); if (s < BIN_CAP) pay[r4.x * BIN_CAP + s] = make_int2(c4.x, __float_as_int(v4.x)); }
                if (r4.y >= rlo && r4.y < rhi) { int s = atomicAdd(&cnt[r4.y], 1); if (s < BIN_CAP) pay[r4.y * BIN_CAP + s] = make_int2(c4.y, __float_as_int(v4.y)); }
                if (r4.z >= rlo && r4.z < rhi) { int s = atomicAdd(&cnt[r4.z], 1); if (s < BIN_CAP) pay[r4.z * BIN_CAP + s] = make_int2(c4.z, __float_as_int(v4.z)); }
                if (r4.w >= rlo && r4.w < rhi) { int s = atomicAdd(&cnt[r4.w], 1); if (s < BIN_CAP) pay[r4.w * BIN_CAP + s] = make_int2(c4.w, __float_as_int(v4.w)); }
            }
        }
    }

    __threadfence();
    grid.sync();

    // ---------------- phase 2: per-row gather-reduce ----------------
    const int lane = tid & 63;
    for (int g = blockIdx.x; g < (N_NODES + 3) / 4; g += gridDim.x) {
        const int row = g * 4 + (tid >> 6);
        if (row >= N_NODES) continue;
        const int n = min(cnt[row], BIN_CAP);
        int2 p = make_int2(0, 0);
        if (lane < n) p = pay[(long)row * BIN_CAP + lane];
        float acc = bias[lane];
        int k = 0;
        for (; k + 8 <= n; k += 8) {
            float gg[8], vv[8];
            #pragma unroll
            for (int j = 0; j < 8; ++j) {
                const int c = __shfl(p.x, k + j, 64);
                vv[j] = __int_as_float(__shfl(p.y, k + j, 64));
                gg[j] = support[(long)c * OUT_SIZE + lane];
            }
            #pragma unroll
            for (int j = 0; j < 8; ++j) acc += gg[j] * vv[j];
        }
        for (; k < n; ++k) {
            const int c = __shfl(p.x, k, 64);
            const float v = __int_as_float(__shfl(p.y, k, 64));
            acc += support[(long)c * OUT_SIZE + lane] * v;
        }
        out[(long)row * OUT_SIZE + lane] = acc;
    }
}

// =========================================================================
// Fallback path (R6/R8 known-good fp32): memset + fused_gemm_bin + reduce
// =========================================================================
#define KC 32
#define KPAD 36
#define G_GEMM NGEMM
#define G_BIN  ((N_EDGES / 4 + 255) / 256)

__global__ __launch_bounds__(256) void fused_gemm_bin(
        const float* __restrict__ x, const float* __restrict__ w,
        float* __restrict__ support,
        const int* __restrict__ rows, const int* __restrict__ cols,
        const float* __restrict__ vals,
        int* __restrict__ cnt, int2* __restrict__ pay) {
    __shared__ float xs[BM][KPAD];
    __shared__ float wt[4][OUT_SIZE][32];
    const int tid = threadIdx.x;

    if (blockIdx.x < G_GEMM) {
        const int row0 = blockIdx.x * BM;
        #pragma unroll
        for (int i = 0; i < 8; ++i) {
            const int f  = tid + 256 * i;
            const int k  = f >> 4;
            const int c0 = (f & 15) << 2;
            const float4 wv = ((const float4*)w)[f];
            const int kk = k & 31;
            const int sw = (((kk >> 2) ^ (f & 7)) << 2) + (kk & 3);
            wt[k >> 5][c0 + 0][sw] = wv.x;
            wt[k >> 5][c0 + 1][sw] = wv.y;
            wt[k >> 5][c0 + 2][sw] = wv.z;
            wt[k >> 5][c0 + 3][sw] = wv.w;
        }
        float4 xreg[4];
        #pragma unroll
        for (int i = 0; i < 4; ++i) {
            const int f = tid + 256 * i;
            int r = row0 + (f >> 3);
            if (r >= N_NODES) r = N_NODES - 1;
            xreg[i] = *(const float4*)(x + (long)r * IN_SIZE + ((f & 7) << 2));
        }
        const int rg = tid & 15;
        const int c0r = (tid >> 4) << 2;
        const int m7  = (tid >> 4) & 7;
        float4 acc[8];
        #pragma unroll
        for (int i = 0; i < 8; ++i) acc[i] = make_float4(0.f, 0.f, 0.f, 0.f);
        for (int kc = 0; kc < 4; ++kc) {
            __syncthreads();
            #pragma unroll
            for (int i = 0; i < 4; ++i) {
                const int f = tid + 256 * i;
                *(float4*)&xs[f >> 3][(f & 7) << 2] = xreg[i];
            }
            __syncthreads();
            if (kc < 3) {
                #pragma unroll
                for (int i = 0; i < 4; ++i) {
                    const int f = tid + 256 * i;
                    int r = row0 + (f >> 3);
                    if (r >= N_NODES) r = N_NODES - 1;
                    xreg[i] = *(const float4*)(x + (long)r * IN_SIZE + (kc + 1) * KC + ((f & 7) << 2));
                }
            }
            #pragma unroll
            for (int k4 = 0; k4 < 8; ++k4) {
                const int so = (k4 ^ m7) << 2;
                const float4 w0 = *(const float4*)&wt[kc][c0r + 0][so];
                const float4 w1 = *(const float4*)&wt[kc][c0r + 1][so];
                const float4 w2 = *(const float4*)&wt[kc][c0r + 2][so];
                const float4 w3 = *(const float4*)&wt[kc][c0r + 3][so];
                #pragma unroll
                for (int i = 0; i < 8; ++i) {
                    const float4 xv = *(const float4*)&xs[rg + (i << 4)][k4 << 2];
                    acc[i].x += xv.x * w0.x + xv.y * w0.y + xv.z * w0.z + xv.w * w0.w;
                    acc[i].y += xv.x * w1.x + xv.y * w1.y + xv.z * w1.z + xv.w * w1.w;
                    acc[i].z += xv.x * w2.x + xv.y * w2.y + xv.z * w2.z + xv.w * w2.w;
                    acc[i].w += xv.x * w3.x + xv.y * w3.y + xv.z * w3.z + xv.w * w3.w;
                }
            }
        }
        #pragma unroll
        for (int i = 0; i < 8; ++i) {
            const int r = row0 + rg + (i << 4);
            if (r < N_NODES)
                *(float4*)(support + (long)r * OUT_SIZE + c0r) = acc[i];
        }
    } else {
        const int i  = (blockIdx.x - G_GEMM) * 256 + tid;
        const int e0 = i * 4;
        if (e0 + 4 <= N_EDGES) {
            const int4   r4 = ((const int4*)rows)[i];
            const int4   c4 = ((const int4*)cols)[i];
            const float4 v4 = ((const float4*)vals)[i];
            int s;
            s = atomicAdd(&cnt[r4.x], 1); if (s < BIN_CAP) pay[r4.x * BIN_CAP + s] = make_int2(c4.x, __float_as_int(v4.x));
            s = atomicAdd(&cnt[r4.y], 1); if (s < BIN_CAP) pay[r4.y * BIN_CAP + s] = make_int2(c4.y, __float_as_int(v4.y));
            s = atomicAdd(&cnt[r4.z], 1); if (s < BIN_CAP) pay[r4.z * BIN_CAP + s] = make_int2(c4.z, __float_as_int(v4.z));
            s = atomicAdd(&cnt[r4.w], 1); if (s < BIN_CAP) pay[r4.w * BIN_CAP + s] = make_int2(c4.w, __float_as_int(v4.w));
        } else {
            for (int e = e0; e < N_EDGES; ++e) {
                const int r = rows[e];
                const int s = atomicAdd(&cnt[r], 1);
                if (s < BIN_CAP) pay[r * BIN_CAP + s] = make_int2(cols[e], __float_as_int(vals[e]));
            }
        }
    }
}

__global__ __launch_bounds__(256) void reduce_rows_pay(const float* __restrict__ support,
                                                       const int* __restrict__ cnt,
                                                       const int2* __restrict__ pay,
                                                       const float* __restrict__ bias,
                                                       float* __restrict__ out) {
    const int tid  = threadIdx.x;
    const int lane = tid & 63;
    const int row  = blockIdx.x * 4 + (tid >> 6);
    if (row >= N_NODES) return;
    const int n = min(cnt[row], BIN_CAP);
    int2 p = make_int2(0, 0);
    if (lane < n) p = pay[(long)row * BIN_CAP + lane];
    float acc = bias[lane];
    int k = 0;
    for (; k + 8 <= n; k += 8) {
        float g[8], v[8];
        #pragma unroll
        for (int j = 0; j < 8; ++j) {
            const int c = __shfl(p.x, k + j, 64);
            v[j] = __int_as_float(__shfl(p.y, k + j, 64));
            g[j] = support[(long)c * OUT_SIZE + lane];
        }
        #pragma unroll
        for (int j = 0; j < 8; ++j) acc += g[j] * v[j];
    }
    for (; k < n; ++k) {
        const int c = __shfl(p.x, k, 64);
        const float v = __int_as_float(__shfl(p.y, k, 64));
        acc += support[(long)c * OUT_SIZE + lane] * v;
    }
    out[(long)row * OUT_SIZE + lane] = acc;
}

// =========================================================================
extern "C" void kernel_launch(void* const* d_in, const int* in_sizes, int n_in,
                              void* d_out, int out_size, void* d_ws, size_t ws_size,
                              hipStream_t stream) {
    const float* x      = (const float*)d_in[0];
    const int*   rows   = (const int*)d_in[1];
    const int*   cols   = (const int*)d_in[2];
    const float* vals   = (const float*)d_in[3];
    const float* weight = (const float*)d_in[4];
    const float* bias   = (const float*)d_in[5];
    float*       out    = (float*)d_out;

    const size_t support_bytes = (size_t)N_NODES * OUT_SIZE * sizeof(float); // 12.8 MB
    const size_t cnt_bytes     = (size_t)N_NODES * sizeof(int);              // 0.2 MB
    const size_t pay_bytes     = (size_t)N_NODES * BIN_CAP * sizeof(int2);   // 25.6 MB

    float* support = (float*)d_ws;
    int*   cnt     = (int*)((char*)d_ws + support_bytes);
    int2*  pay     = (int2*)((char*)d_ws + support_bytes + cnt_bytes);
    int*   q       = (int*)((char*)d_ws + support_bytes + cnt_bytes + pay_bytes);

    if (ws_size >= support_bytes + cnt_bytes + pay_bytes + 1024) {
        int occ = 0;
        if (hipOccupancyMaxActiveBlocksPerMultiprocessor(&occ, gcn_coop, 256, 0)
                == hipSuccess && occ > 0) {
            if (occ > 4) occ = 4;
            int nblocks = occ * 256;            // 256 CUs on MI355X
            void* args[] = {(void*)&x, (void*)&weight, (void*)&rows, (void*)&cols,
                            (void*)&vals, (void*)&bias, (void*)&support, (void*)&cnt,
                            (void*)&pay, (void*)&q, (void*)&out};
            if (hipLaunchCooperativeKernel((void*)gcn_coop, dim3(nblocks), dim3(256),
                                           args, 0, stream) == hipSuccess)
                return;
        }
        hipMemsetAsync(cnt, 0, cnt_bytes, stream);
        fused_gemm_bin<<<G_GEMM + G_BIN, 256, 0, stream>>>(x, weight, support,
                                                           rows, cols, vals, cnt, pay);
        reduce_rows_pay<<<(N_NODES + 3) / 4, 256, 0, stream>>>(support, cnt, pay, bias, out);
        return;
    }

    hipMemsetAsync(cnt, 0, cnt_bytes, stream);
    fused_gemm_bin<<<G_GEMM + G_BIN, 256, 0, stream>>>(x, weight, support,
                                                       rows, cols, vals, cnt, pay);
    reduce_rows_pay<<<(N_NODES + 3) / 4, 256, 0, stream>>>(support, cnt, pay, bias, out);
}

// Round 10
// 277.729 us; speedup vs baseline: 1.1507x; 1.1507x over previous
//
#include <hip/hip_runtime.h>
#include <hip/hip_cooperative_groups.h>

namespace cg = cooperative_groups;

#define N_NODES 50000
#define N_EDGES 800000
#define IN_SIZE 128
#define OUT_SIZE 64
#define BIN_CAP 64   // Poisson(16) => P(>=64) ~ 2e-18

#define BM 128
#define NGEMM ((N_NODES + BM - 1) / BM)      // 391 gemm tiles
#define NCH   (N_EDGES / 4)                  // 200000 int4 edge-groups
#define NBIN  ((NCH + 255) / 256)            // 782 bin chunks
#define NTASK (NGEMM + NBIN)

typedef __attribute__((ext_vector_type(8))) short short8v;  // 8 bf16 (4 VGPRs)
typedef __attribute__((ext_vector_type(4))) float f32x4;

__device__ __forceinline__ unsigned short f2bf(float f) {    // RTNE fp32->bf16
    unsigned u = __float_as_uint(f);
    return (unsigned short)((u + 0x7fffu + ((u >> 16) & 1u)) >> 16);
}
__device__ __forceinline__ unsigned pk2(float a, float b) {  // pack 2 bf16
    return (unsigned)f2bf(a) | ((unsigned)f2bf(b) << 16);
}

// =========================================================================
// Cooperative kernel:
//  phase0: zero cnt + queue
//  phase1: ONE dynamic queue; task<NGEMM -> MFMA bf16 gemm tile,
//          else -> bin chunk (processed exactly once; R9's XCD-local
//          8-queue scan was disproven: 8x reads, no write gain)
//  phase2: per-row gather-reduce (+bias)
// NO min-waves cap (R7: capping spills accumulators -> 6x regression).
// =========================================================================
__global__ __launch_bounds__(256) void gcn_coop(
        const float* __restrict__ x, const float* __restrict__ w,
        const int* __restrict__ rows, const int* __restrict__ cols,
        const float* __restrict__ vals, const float* __restrict__ bias,
        float* __restrict__ support, int* __restrict__ cnt,
        int2* __restrict__ pay, int* __restrict__ q,
        float* __restrict__ out) {
    __shared__ int4 xs4[2048];     // 32 KB: bf16 x-tile, [128 rows][256 B] swizzled
    __shared__ int  wt4[4096];     // 16 KB: bf16 w^T,   [64 cols][256 B] swizzled
    __shared__ int task_s;
    char* xb = (char*)xs4;
    char* wb = (char*)wt4;
    const int tid = threadIdx.x;
    cg::grid_group grid = cg::this_grid();

    // ---------------- phase 0 ----------------
    for (int i = blockIdx.x * 256 + tid; i < N_NODES; i += gridDim.x * 256)
        cnt[i] = 0;
    if (blockIdx.x == 0 && tid == 0) q[0] = 0;
    grid.sync();

    // ---------------- phase 1: dynamic {gemm | bin} tasks ----------------
    bool wloaded = false;
    for (;;) {
        if (tid == 0) task_s = atomicAdd(&q[0], 1);
        __syncthreads();
        const int t = task_s;
        __syncthreads();
        if (t >= NTASK) break;

        if (t < NGEMM) {
            // ---------- MFMA gemm tile ----------
            const int row0 = t * BM;

            // stage x tile -> bf16 LDS, swizzle: byte ^= (row&7)<<4
            #pragma unroll
            for (int i = 0; i < 8; ++i) {
                const int s   = tid + 256 * i;    // s < 2048 (row, 16B-slot)
                const int row = s >> 4;
                const int sl  = s & 15;
                int r = row0 + row; if (r > N_NODES - 1) r = N_NODES - 1;
                const float4* xp = (const float4*)(x + (long)r * IN_SIZE + sl * 8);
                const float4 f0 = xp[0], f1 = xp[1];
                int4 pk;
                pk.x = pk2(f0.x, f0.y); pk.y = pk2(f0.z, f0.w);
                pk.z = pk2(f1.x, f1.y); pk.w = pk2(f1.z, f1.w);
                *(int4*)(xb + row * 256 + ((sl * 16) ^ ((row & 7) << 4))) = pk;
            }
            if (!wloaded) {   // stage w^T once per block (same swizzle on col)
                wloaded = true;
                #pragma unroll
                for (int i = 0; i < 4; ++i) {
                    const int f  = tid + 256 * i;          // f < 1024
                    const int kp = f >> 4;                 // k-pair 0..63
                    const int c0 = (f & 15) << 2;
                    const float4 w0 = *(const float4*)(w + (2 * kp) * OUT_SIZE + c0);
                    const float4 w1 = *(const float4*)(w + (2 * kp + 1) * OUT_SIZE + c0);
                    const float a0[4] = {w0.x, w0.y, w0.z, w0.w};
                    const float a1[4] = {w1.x, w1.y, w1.z, w1.w};
                    #pragma unroll
                    for (int j = 0; j < 4; ++j) {
                        const int c = c0 + j;
                        *(unsigned*)(wb + c * 256 + ((kp * 4) ^ ((c & 7) << 4))) =
                            pk2(a0[j], a1[j]);
                    }
                }
            }
            __syncthreads();

            // wave wv owns rows [wv*32, wv*32+32) x all 64 cols
            const int l   = tid & 63;
            const int wv  = tid >> 6;
            const int rb  = wv * 32;
            const int lm  = l & 15;
            const int swz = (l & 7) << 4;
            f32x4 acc[2][4];
            #pragma unroll
            for (int a16 = 0; a16 < 2; ++a16)
                #pragma unroll
                for (int nb = 0; nb < 4; ++nb)
                    acc[a16][nb] = (f32x4){0.f, 0.f, 0.f, 0.f};

            #pragma unroll
            for (int kk = 0; kk < 4; ++kk) {
                const int ko = ((kk << 6) + ((l >> 4) << 4)) ^ swz;
                const short8v a0 = *(const short8v*)(xb + (rb + lm) * 256 + ko);
                const short8v a1 = *(const short8v*)(xb + (rb + 16 + lm) * 256 + ko);
                const short8v b0 = *(const short8v*)(wb + lm * 256 + ko);
                const short8v b1 = *(const short8v*)(wb + (16 + lm) * 256 + ko);
                const short8v b2 = *(const short8v*)(wb + (32 + lm) * 256 + ko);
                const short8v b3 = *(const short8v*)(wb + (48 + lm) * 256 + ko);
                acc[0][0] = __builtin_amdgcn_mfma_f32_16x16x32_bf16(a0, b0, acc[0][0], 0, 0, 0);
                acc[0][1] = __builtin_amdgcn_mfma_f32_16x16x32_bf16(a0, b1, acc[0][1], 0, 0, 0);
                acc[0][2] = __builtin_amdgcn_mfma_f32_16x16x32_bf16(a0, b2, acc[0][2], 0, 0, 0);
                acc[0][3] = __builtin_amdgcn_mfma_f32_16x16x32_bf16(a0, b3, acc[0][3], 0, 0, 0);
                acc[1][0] = __builtin_amdgcn_mfma_f32_16x16x32_bf16(a1, b0, acc[1][0], 0, 0, 0);
                acc[1][1] = __builtin_amdgcn_mfma_f32_16x16x32_bf16(a1, b1, acc[1][1], 0, 0, 0);
                acc[1][2] = __builtin_amdgcn_mfma_f32_16x16x32_bf16(a1, b2, acc[1][2], 0, 0, 0);
                acc[1][3] = __builtin_amdgcn_mfma_f32_16x16x32_bf16(a1, b3, acc[1][3], 0, 0, 0);
            }
            __syncthreads();   // all LDS reads done before next task restages

            // C/D layout (m89-verified): col = lane&15, row = (lane>>4)*4 + reg
            const int rr = (l >> 4) << 2;
            #pragma unroll
            for (int a16 = 0; a16 < 2; ++a16) {
                #pragma unroll
                for (int r4 = 0; r4 < 4; ++r4) {
                    const int grow = row0 + rb + a16 * 16 + rr + r4;
                    if (grow < N_NODES) {
                        #pragma unroll
                        for (int nb = 0; nb < 4; ++nb)
                            support[(long)grow * OUT_SIZE + nb * 16 + lm] = acc[a16][nb][r4];
                    }
                }
            }
        } else {
            // ---------- bin chunk (each processed exactly once) ----------
            const int i = (t - NGEMM) * 256 + tid;
            if (i < NCH) {
                const int4   r4 = ((const int4*)rows)[i];
                const int4   c4 = ((const int4*)cols)[i];
                const float4 v4 = ((const float4*)vals)[i];
                int s;
                s = atomicAdd(&cnt[r4.x], 1); if (s < BIN_CAP) pay[r4.x * BIN_CAP + s] = make_int2(c4.x, __float_as_int(v4.x));
                s = atomicAdd(&cnt[r4.y], 1); if (s < BIN_CAP) pay[r4.y * BIN_CAP + s] = make_int2(c4.y, __float_as_int(v4.y));
                s = atomicAdd(&cnt[r4.z], 1); if (s < BIN_CAP) pay[r4.z * BIN_CAP + s] = make_int2(c4.z, __float_as_int(v4.z));
                s = atomicAdd(&cnt[r4.w], 1); if (s < BIN_CAP) pay[r4.w * BIN_CAP + s] = make_int2(c4.w, __float_as_int(v4.w));
            }
        }
    }

    __threadfence();
    grid.sync();

    // ---------------- phase 2: per-row gather-reduce ----------------
    const int lane = tid & 63;
    for (int g = blockIdx.x; g < (N_NODES + 3) / 4; g += gridDim.x) {
        const int row = g * 4 + (tid >> 6);
        if (row >= N_NODES) continue;
        const int n = min(cnt[row], BIN_CAP);
        int2 p = make_int2(0, 0);
        if (lane < n) p = pay[(long)row * BIN_CAP + lane];
        float acc = bias[lane];
        int k = 0;
        for (; k + 8 <= n; k += 8) {
            float gg[8], vv[8];
            #pragma unroll
            for (int j = 0; j < 8; ++j) {
                const int c = __shfl(p.x, k + j, 64);
                vv[j] = __int_as_float(__shfl(p.y, k + j, 64));
                gg[j] = support[(long)c * OUT_SIZE + lane];
            }
            #pragma unroll
            for (int j = 0; j < 8; ++j) acc += gg[j] * vv[j];
        }
        for (; k < n; ++k) {
            const int c = __shfl(p.x, k, 64);
            const float v = __int_as_float(__shfl(p.y, k, 64));
            acc += support[(long)c * OUT_SIZE + lane] * v;
        }
        out[(long)row * OUT_SIZE + lane] = acc;
    }
}

// =========================================================================
// Fallback path (R6 known-good fp32): memset + fused_gemm_bin + reduce
// =========================================================================
#define KC 32
#define KPAD 36
#define G_GEMM NGEMM
#define G_BIN  ((N_EDGES / 4 + 255) / 256)

__global__ __launch_bounds__(256) void fused_gemm_bin(
        const float* __restrict__ x, const float* __restrict__ w,
        float* __restrict__ support,
        const int* __restrict__ rows, const int* __restrict__ cols,
        const float* __restrict__ vals,
        int* __restrict__ cnt, int2* __restrict__ pay) {
    __shared__ float xs[BM][KPAD];
    __shared__ float wt[4][OUT_SIZE][32];
    const int tid = threadIdx.x;

    if (blockIdx.x < G_GEMM) {
        const int row0 = blockIdx.x * BM;
        #pragma unroll
        for (int i = 0; i < 8; ++i) {
            const int f  = tid + 256 * i;
            const int k  = f >> 4;
            const int c0 = (f & 15) << 2;
            const float4 wv = ((const float4*)w)[f];
            const int kk = k & 31;
            const int sw = (((kk >> 2) ^ (f & 7)) << 2) + (kk & 3);
            wt[k >> 5][c0 + 0][sw] = wv.x;
            wt[k >> 5][c0 + 1][sw] = wv.y;
            wt[k >> 5][c0 + 2][sw] = wv.z;
            wt[k >> 5][c0 + 3][sw] = wv.w;
        }
        float4 xreg[4];
        #pragma unroll
        for (int i = 0; i < 4; ++i) {
            const int f = tid + 256 * i;
            int r = row0 + (f >> 3);
            if (r >= N_NODES) r = N_NODES - 1;
            xreg[i] = *(const float4*)(x + (long)r * IN_SIZE + ((f & 7) << 2));
        }
        const int rg = tid & 15;
        const int c0r = (tid >> 4) << 2;
        const int m7  = (tid >> 4) & 7;
        float4 acc[8];
        #pragma unroll
        for (int i = 0; i < 8; ++i) acc[i] = make_float4(0.f, 0.f, 0.f, 0.f);
        for (int kc = 0; kc < 4; ++kc) {
            __syncthreads();
            #pragma unroll
            for (int i = 0; i < 4; ++i) {
                const int f = tid + 256 * i;
                *(float4*)&xs[f >> 3][(f & 7) << 2] = xreg[i];
            }
            __syncthreads();
            if (kc < 3) {
                #pragma unroll
                for (int i = 0; i < 4; ++i) {
                    const int f = tid + 256 * i;
                    int r = row0 + (f >> 3);
                    if (r >= N_NODES) r = N_NODES - 1;
                    xreg[i] = *(const float4*)(x + (long)r * IN_SIZE + (kc + 1) * KC + ((f & 7) << 2));
                }
            }
            #pragma unroll
            for (int k4 = 0; k4 < 8; ++k4) {
                const int so = (k4 ^ m7) << 2;
                const float4 w0 = *(const float4*)&wt[kc][c0r + 0][so];
                const float4 w1 = *(const float4*)&wt[kc][c0r + 1][so];
                const float4 w2 = *(const float4*)&wt[kc][c0r + 2][so];
                const float4 w3 = *(const float4*)&wt[kc][c0r + 3][so];
                #pragma unroll
                for (int i = 0; i < 8; ++i) {
                    const float4 xv = *(const float4*)&xs[rg + (i << 4)][k4 << 2];
                    acc[i].x += xv.x * w0.x + xv.y * w0.y + xv.z * w0.z + xv.w * w0.w;
                    acc[i].y += xv.x * w1.x + xv.y * w1.y + xv.z * w1.z + xv.w * w1.w;
                    acc[i].z += xv.x * w2.x + xv.y * w2.y + xv.z * w2.z + xv.w * w2.w;
                    acc[i].w += xv.x * w3.x + xv.y * w3.y + xv.z * w3.z + xv.w * w3.w;
                }
            }
        }
        #pragma unroll
        for (int i = 0; i < 8; ++i) {
            const int r = row0 + rg + (i << 4);
            if (r < N_NODES)
                *(float4*)(support + (long)r * OUT_SIZE + c0r) = acc[i];
        }
    } else {
        const int i  = (blockIdx.x - G_GEMM) * 256 + tid;
        const int e0 = i * 4;
        if (e0 + 4 <= N_EDGES) {
            const int4   r4 = ((const int4*)rows)[i];
            const int4   c4 = ((const int4*)cols)[i];
            const float4 v4 = ((const float4*)vals)[i];
            int s;
            s = atomicAdd(&cnt[r4.x], 1); if (s < BIN_CAP) pay[r4.x * BIN_CAP + s] = make_int2(c4.x, __float_as_int(v4.x));
            s = atomicAdd(&cnt[r4.y], 1); if (s < BIN_CAP) pay[r4.y * BIN_CAP + s] = make_int2(c4.y, __float_as_int(v4.y));
            s = atomicAdd(&cnt[r4.z], 1); if (s < BIN_CAP) pay[r4.z * BIN_CAP + s] = make_int2(c4.z, __float_as_int(v4.z));
            s = atomicAdd(&cnt[r4.w], 1); if (s < BIN_CAP) pay[r4.w * BIN_CAP + s] = make_int2(c4.w, __float_as_int(v4.w));
        } else {
            for (int e = e0; e < N_EDGES; ++e) {
                const int r = rows[e];
                const int s = atomicAdd(&cnt[r], 1);
                if (s < BIN_CAP) pay[r * BIN_CAP + s] = make_int2(cols[e], __float_as_int(vals[e]));
            }
        }
    }
}

__global__ __launch_bounds__(256) void reduce_rows_pay(const float* __restrict__ support,
                                                       const int* __restrict__ cnt,
                                                       const int2* __restrict__ pay,
                                                       const float* __restrict__ bias,
                                                       float* __restrict__ out) {
    const int tid  = threadIdx.x;
    const int lane = tid & 63;
    const int row  = blockIdx.x * 4 + (tid >> 6);
    if (row >= N_NODES) return;
    const int n = min(cnt[row], BIN_CAP);
    int2 p = make_int2(0, 0);
    if (lane < n) p = pay[(long)row * BIN_CAP + lane];
    float acc = bias[lane];
    int k = 0;
    for (; k + 8 <= n; k += 8) {
        float g[8], v[8];
        #pragma unroll
        for (int j = 0; j < 8; ++j) {
            const int c = __shfl(p.x, k + j, 64);
            v[j] = __int_as_float(__shfl(p.y, k + j, 64));
            g[j] = support[(long)c * OUT_SIZE + lane];
        }
        #pragma unroll
        for (int j = 0; j < 8; ++j) acc += g[j] * v[j];
    }
    for (; k < n; ++k) {
        const int c = __shfl(p.x, k, 64);
        const float v = __int_as_float(__shfl(p.y, k, 64));
        acc += support[(long)c * OUT_SIZE + lane] * v;
    }
    out[(long)row * OUT_SIZE + lane] = acc;
}

// =========================================================================
extern "C" void kernel_launch(void* const* d_in, const int* in_sizes, int n_in,
                              void* d_out, int out_size, void* d_ws, size_t ws_size,
                              hipStream_t stream) {
    const float* x      = (const float*)d_in[0];
    const int*   rows   = (const int*)d_in[1];
    const int*   cols   = (const int*)d_in[2];
    const float* vals   = (const float*)d_in[3];
    const float* weight = (const float*)d_in[4];
    const float* bias   = (const float*)d_in[5];
    float*       out    = (float*)d_out;

    const size_t support_bytes = (size_t)N_NODES * OUT_SIZE * sizeof(float); // 12.8 MB
    const size_t cnt_bytes     = (size_t)N_NODES * sizeof(int);              // 0.2 MB
    const size_t pay_bytes     = (size_t)N_NODES * BIN_CAP * sizeof(int2);   // 25.6 MB

    float* support = (float*)d_ws;
    int*   cnt     = (int*)((char*)d_ws + support_bytes);
    int2*  pay     = (int2*)((char*)d_ws + support_bytes + cnt_bytes);
    int*   q       = (int*)((char*)d_ws + support_bytes + cnt_bytes + pay_bytes);

    if (ws_size >= support_bytes + cnt_bytes + pay_bytes + 1024) {
        int occ = 0;
        if (hipOccupancyMaxActiveBlocksPerMultiprocessor(&occ, gcn_coop, 256, 0)
                == hipSuccess && occ > 0) {
            if (occ > 4) occ = 4;
            int nblocks = occ * 256;            // 256 CUs on MI355X
            void* args[] = {(void*)&x, (void*)&weight, (void*)&rows, (void*)&cols,
                            (void*)&vals, (void*)&bias, (void*)&support, (void*)&cnt,
                            (void*)&pay, (void*)&q, (void*)&out};
            if (hipLaunchCooperativeKernel((void*)gcn_coop, dim3(nblocks), dim3(256),
                                           args, 0, stream) == hipSuccess)
                return;
        }
        hipMemsetAsync(cnt, 0, cnt_bytes, stream);
        fused_gemm_bin<<<G_GEMM + G_BIN, 256, 0, stream>>>(x, weight, support,
                                                           rows, cols, vals, cnt, pay);
        reduce_rows_pay<<<(N_NODES + 3) / 4, 256, 0, stream>>>(support, cnt, pay, bias, out);
        return;
    }

    hipMemsetAsync(cnt, 0, cnt_bytes, stream);
    fused_gemm_bin<<<G_GEMM + G_BIN, 256, 0, stream>>>(x, weight, support,
                                                       rows, cols, vals, cnt, pay);
    reduce_rows_pay<<<(N_NODES + 3) / 4, 256, 0, stream>>>(support, cnt, pay, bias, out);
}

// Round 11
// 104.091 us; speedup vs baseline: 3.0703x; 2.6681x over previous
//
#include <hip/hip_runtime.h>
#include <hip/hip_cooperative_groups.h>

namespace cg = cooperative_groups;

#define N_NODES 50000
#define N_EDGES 800000
#define IN_SIZE 128
#define OUT_SIZE 64
#define BIN_CAP 64   // Poisson(16) => P(>=64) ~ 2e-18

#define BM 128
#define KC 32
#define KPAD 36
#define NGEMM ((N_NODES + BM - 1) / BM)      // 391 gemm tiles
#define NCH   (N_EDGES / 4)                  // 200000 int4 edge-groups
#define NBIN  ((NCH + 255) / 256)            // 782 bin chunks
#define NTASK (NGEMM + NBIN)

__device__ __forceinline__ unsigned short f2bf(float f) {    // RTNE fp32->bf16
    unsigned u = __float_as_uint(f);
    return (unsigned short)((u + 0x7fffu + ((u >> 16) & 1u)) >> 16);
}
// pay entry: low 16 = col, high 16 = bf16(val). unpack val = bits & 0xFFFF0000.
__device__ __forceinline__ unsigned pack_cv(int c, float v) {
    return (unsigned)c | ((unsigned)f2bf(v) << 16);
}

// =========================================================================
// Cooperative kernel (R8 structure, proven 105us; ONLY delta: 4-byte pay):
//  phase0: zero cnt + queue
//  phase1: ONE dynamic queue; t<NGEMM -> fp32 VALU gemm tile, else bin chunk
//  phase2: per-row gather-reduce (+bias)
// NO min-waves cap (R7: capping spills accumulators -> 6x regression).
// MFMA gemm inside coop regressed 2.6x unexplained (R9/R10) -> reverted.
// =========================================================================
__global__ __launch_bounds__(256) void gcn_coop(
        const float* __restrict__ x, const float* __restrict__ w,
        const int* __restrict__ rows, const int* __restrict__ cols,
        const float* __restrict__ vals, const float* __restrict__ bias,
        float* __restrict__ support, int* __restrict__ cnt,
        unsigned* __restrict__ pay, int* __restrict__ q,
        float* __restrict__ out) {
    __shared__ float xs[BM][KPAD];           // 18.4 KB
    __shared__ float wt[4][OUT_SIZE][32];    // 32.0 KB, swizzled
    __shared__ int task_s;
    const int tid = threadIdx.x;
    cg::grid_group grid = cg::this_grid();

    // ---------------- phase 0: zero counters ----------------
    for (int i = blockIdx.x * 256 + tid; i < N_NODES; i += gridDim.x * 256)
        cnt[i] = 0;
    if (blockIdx.x == 0 && tid == 0) q[0] = 0;
    grid.sync();

    // ---------------- phase 1: dynamic {gemm | bin} tasks ----------------
    bool wloaded = false;
    for (;;) {
        if (tid == 0) task_s = atomicAdd(&q[0], 1);
        __syncthreads();
        const int t = task_s;
        __syncthreads();                     // protect task_s before next write
        if (t >= NTASK) break;

        if (t < NGEMM) {
            // ---------- fp32 VALU gemm tile (R8-proven) ----------
            const int row0 = t * BM;
            if (!wloaded) {
                wloaded = true;
                #pragma unroll
                for (int i = 0; i < 8; ++i) {
                    const int f  = tid + 256 * i;
                    const int k  = f >> 4;
                    const int c0 = (f & 15) << 2;
                    const float4 wv = ((const float4*)w)[f];
                    const int kk = k & 31;
                    const int sw = (((kk >> 2) ^ (f & 7)) << 2) + (kk & 3);
                    wt[k >> 5][c0 + 0][sw] = wv.x;
                    wt[k >> 5][c0 + 1][sw] = wv.y;
                    wt[k >> 5][c0 + 2][sw] = wv.z;
                    wt[k >> 5][c0 + 3][sw] = wv.w;
                }
            }
            float4 xreg[4];
            #pragma unroll
            for (int i = 0; i < 4; ++i) {
                const int f = tid + 256 * i;             // row=f>>3, koff=(f&7)*4
                int r = row0 + (f >> 3);
                if (r >= N_NODES) r = N_NODES - 1;
                xreg[i] = *(const float4*)(x + (long)r * IN_SIZE + ((f & 7) << 2));
            }
            const int rg = tid & 15;
            const int c0r = (tid >> 4) << 2;
            const int m7  = (tid >> 4) & 7;
            float4 acc[8];
            #pragma unroll
            for (int i = 0; i < 8; ++i) acc[i] = make_float4(0.f, 0.f, 0.f, 0.f);

            for (int kc = 0; kc < 4; ++kc) {
                __syncthreads();
                #pragma unroll
                for (int i = 0; i < 4; ++i) {
                    const int f = tid + 256 * i;
                    *(float4*)&xs[f >> 3][(f & 7) << 2] = xreg[i];
                }
                __syncthreads();
                if (kc < 3) {
                    #pragma unroll
                    for (int i = 0; i < 4; ++i) {
                        const int f = tid + 256 * i;
                        int r = row0 + (f >> 3);
                        if (r >= N_NODES) r = N_NODES - 1;
                        xreg[i] = *(const float4*)(x + (long)r * IN_SIZE + (kc + 1) * KC + ((f & 7) << 2));
                    }
                }
                #pragma unroll
                for (int k4 = 0; k4 < 8; ++k4) {
                    const int so = (k4 ^ m7) << 2;
                    const float4 w0 = *(const float4*)&wt[kc][c0r + 0][so];
                    const float4 w1 = *(const float4*)&wt[kc][c0r + 1][so];
                    const float4 w2 = *(const float4*)&wt[kc][c0r + 2][so];
                    const float4 w3 = *(const float4*)&wt[kc][c0r + 3][so];
                    #pragma unroll
                    for (int i = 0; i < 8; ++i) {
                        const float4 xv = *(const float4*)&xs[rg + (i << 4)][k4 << 2];
                        acc[i].x += xv.x * w0.x + xv.y * w0.y + xv.z * w0.z + xv.w * w0.w;
                        acc[i].y += xv.x * w1.x + xv.y * w1.y + xv.z * w1.z + xv.w * w1.w;
                        acc[i].z += xv.x * w2.x + xv.y * w2.y + xv.z * w2.z + xv.w * w2.w;
                        acc[i].w += xv.x * w3.x + xv.y * w3.y + xv.z * w3.z + xv.w * w3.w;
                    }
                }
            }
            #pragma unroll
            for (int i = 0; i < 8; ++i) {
                const int r = row0 + rg + (i << 4);
                if (r < N_NODES)
                    *(float4*)(support + (long)r * OUT_SIZE + c0r) = acc[i];
            }
            __syncthreads();   // xs safety before next task restages
        } else {
            // ---------- bin chunk (4-byte packed payload) ----------
            const int i = (t - NGEMM) * 256 + tid;
            if (i < NCH) {
                const int4   r4 = ((const int4*)rows)[i];
                const int4   c4 = ((const int4*)cols)[i];
                const float4 v4 = ((const float4*)vals)[i];
                int s;
                s = atomicAdd(&cnt[r4.x], 1); if (s < BIN_CAP) pay[r4.x * BIN_CAP + s] = pack_cv(c4.x, v4.x);
                s = atomicAdd(&cnt[r4.y], 1); if (s < BIN_CAP) pay[r4.y * BIN_CAP + s] = pack_cv(c4.y, v4.y);
                s = atomicAdd(&cnt[r4.z], 1); if (s < BIN_CAP) pay[r4.z * BIN_CAP + s] = pack_cv(c4.z, v4.z);
                s = atomicAdd(&cnt[r4.w], 1); if (s < BIN_CAP) pay[r4.w * BIN_CAP + s] = pack_cv(c4.w, v4.w);
            }
        }
    }

    __threadfence();
    grid.sync();

    // ---------------- phase 2: per-row gather-reduce ----------------
    const int lane = tid & 63;
    for (int g = blockIdx.x; g < (N_NODES + 3) / 4; g += gridDim.x) {
        const int row = g * 4 + (tid >> 6);
        if (row >= N_NODES) continue;
        const int n = min(cnt[row], BIN_CAP);
        unsigned p = 0;
        if (lane < n) p = pay[(long)row * BIN_CAP + lane];   // coalesced 256B/wave
        float acc = bias[lane];
        int k = 0;
        for (; k + 8 <= n; k += 8) {
            float gg[8], vv[8];
            #pragma unroll
            for (int j = 0; j < 8; ++j) {
                const unsigned pk = (unsigned)__shfl((int)p, k + j, 64);
                vv[j] = __uint_as_float(pk & 0xFFFF0000u);
                gg[j] = support[(long)(pk & 0xFFFFu) * OUT_SIZE + lane];
            }
            #pragma unroll
            for (int j = 0; j < 8; ++j) acc += gg[j] * vv[j];
        }
        for (; k < n; ++k) {
            const unsigned pk = (unsigned)__shfl((int)p, k, 64);
            acc += support[(long)(pk & 0xFFFFu) * OUT_SIZE + lane]
                   * __uint_as_float(pk & 0xFFFF0000u);
        }
        out[(long)row * OUT_SIZE + lane] = acc;
    }
}

// =========================================================================
// Fallback path (non-coop): memset + fused_gemm_bin + reduce (4-byte pay)
// =========================================================================
#define G_GEMM NGEMM
#define G_BIN  ((N_EDGES / 4 + 255) / 256)

__global__ __launch_bounds__(256) void fused_gemm_bin(
        const float* __restrict__ x, const float* __restrict__ w,
        float* __restrict__ support,
        const int* __restrict__ rows, const int* __restrict__ cols,
        const float* __restrict__ vals,
        int* __restrict__ cnt, unsigned* __restrict__ pay) {
    __shared__ float xs[BM][KPAD];
    __shared__ float wt[4][OUT_SIZE][32];
    const int tid = threadIdx.x;

    if (blockIdx.x < G_GEMM) {
        const int row0 = blockIdx.x * BM;
        #pragma unroll
        for (int i = 0; i < 8; ++i) {
            const int f  = tid + 256 * i;
            const int k  = f >> 4;
            const int c0 = (f & 15) << 2;
            const float4 wv = ((const float4*)w)[f];
            const int kk = k & 31;
            const int sw = (((kk >> 2) ^ (f & 7)) << 2) + (kk & 3);
            wt[k >> 5][c0 + 0][sw] = wv.x;
            wt[k >> 5][c0 + 1][sw] = wv.y;
            wt[k >> 5][c0 + 2][sw] = wv.z;
            wt[k >> 5][c0 + 3][sw] = wv.w;
        }
        float4 xreg[4];
        #pragma unroll
        for (int i = 0; i < 4; ++i) {
            const int f = tid + 256 * i;
            int r = row0 + (f >> 3);
            if (r >= N_NODES) r = N_NODES - 1;
            xreg[i] = *(const float4*)(x + (long)r * IN_SIZE + ((f & 7) << 2));
        }
        const int rg = tid & 15;
        const int c0r = (tid >> 4) << 2;
        const int m7  = (tid >> 4) & 7;
        float4 acc[8];
        #pragma unroll
        for (int i = 0; i < 8; ++i) acc[i] = make_float4(0.f, 0.f, 0.f, 0.f);
        for (int kc = 0; kc < 4; ++kc) {
            __syncthreads();
            #pragma unroll
            for (int i = 0; i < 4; ++i) {
                const int f = tid + 256 * i;
                *(float4*)&xs[f >> 3][(f & 7) << 2] = xreg[i];
            }
            __syncthreads();
            if (kc < 3) {
                #pragma unroll
                for (int i = 0; i < 4; ++i) {
                    const int f = tid + 256 * i;
                    int r = row0 + (f >> 3);
                    if (r >= N_NODES) r = N_NODES - 1;
                    xreg[i] = *(const float4*)(x + (long)r * IN_SIZE + (kc + 1) * KC + ((f & 7) << 2));
                }
            }
            #pragma unroll
            for (int k4 = 0; k4 < 8; ++k4) {
                const int so = (k4 ^ m7) << 2;
                const float4 w0 = *(const float4*)&wt[kc][c0r + 0][so];
                const float4 w1 = *(const float4*)&wt[kc][c0r + 1][so];
                const float4 w2 = *(const float4*)&wt[kc][c0r + 2][so];
                const float4 w3 = *(const float4*)&wt[kc][c0r + 3][so];
                #pragma unroll
                for (int i = 0; i < 8; ++i) {
                    const float4 xv = *(const float4*)&xs[rg + (i << 4)][k4 << 2];
                    acc[i].x += xv.x * w0.x + xv.y * w0.y + xv.z * w0.z + xv.w * w0.w;
                    acc[i].y += xv.x * w1.x + xv.y * w1.y + xv.z * w1.z + xv.w * w1.w;
                    acc[i].z += xv.x * w2.x + xv.y * w2.y + xv.z * w2.z + xv.w * w2.w;
                    acc[i].w += xv.x * w3.x + xv.y * w3.y + xv.z * w3.z + xv.w * w3.w;
                }
            }
        }
        #pragma unroll
        for (int i = 0; i < 8; ++i) {
            const int r = row0 + rg + (i << 4);
            if (r < N_NODES)
                *(float4*)(support + (long)r * OUT_SIZE + c0r) = acc[i];
        }
    } else {
        const int i = (blockIdx.x - G_GEMM) * 256 + tid;
        if (i < NCH) {
            const int4   r4 = ((const int4*)rows)[i];
            const int4   c4 = ((const int4*)cols)[i];
            const float4 v4 = ((const float4*)vals)[i];
            int s;
            s = atomicAdd(&cnt[r4.x], 1); if (s < BIN_CAP) pay[r4.x * BIN_CAP + s] = pack_cv(c4.x, v4.x);
            s = atomicAdd(&cnt[r4.y], 1); if (s < BIN_CAP) pay[r4.y * BIN_CAP + s] = pack_cv(c4.y, v4.y);
            s = atomicAdd(&cnt[r4.z], 1); if (s < BIN_CAP) pay[r4.z * BIN_CAP + s] = pack_cv(c4.z, v4.z);
            s = atomicAdd(&cnt[r4.w], 1); if (s < BIN_CAP) pay[r4.w * BIN_CAP + s] = pack_cv(c4.w, v4.w);
        }
    }
}

__global__ __launch_bounds__(256) void reduce_rows_pay(const float* __restrict__ support,
                                                       const int* __restrict__ cnt,
                                                       const unsigned* __restrict__ pay,
                                                       const float* __restrict__ bias,
                                                       float* __restrict__ out) {
    const int tid  = threadIdx.x;
    const int lane = tid & 63;
    const int row  = blockIdx.x * 4 + (tid >> 6);
    if (row >= N_NODES) return;
    const int n = min(cnt[row], BIN_CAP);
    unsigned p = 0;
    if (lane < n) p = pay[(long)row * BIN_CAP + lane];
    float acc = bias[lane];
    int k = 0;
    for (; k + 8 <= n; k += 8) {
        float g[8], v[8];
        #pragma unroll
        for (int j = 0; j < 8; ++j) {
            const unsigned pk = (unsigned)__shfl((int)p, k + j, 64);
            v[j] = __uint_as_float(pk & 0xFFFF0000u);
            g[j] = support[(long)(pk & 0xFFFFu) * OUT_SIZE + lane];
        }
        #pragma unroll
        for (int j = 0; j < 8; ++j) acc += g[j] * v[j];
    }
    for (; k < n; ++k) {
        const unsigned pk = (unsigned)__shfl((int)p, k, 64);
        acc += support[(long)(pk & 0xFFFFu) * OUT_SIZE + lane]
               * __uint_as_float(pk & 0xFFFF0000u);
    }
    out[(long)row * OUT_SIZE + lane] = acc;
}

// =========================================================================
extern "C" void kernel_launch(void* const* d_in, const int* in_sizes, int n_in,
                              void* d_out, int out_size, void* d_ws, size_t ws_size,
                              hipStream_t stream) {
    const float* x      = (const float*)d_in[0];
    const int*   rows   = (const int*)d_in[1];
    const int*   cols   = (const int*)d_in[2];
    const float* vals   = (const float*)d_in[3];
    const float* weight = (const float*)d_in[4];
    const float* bias   = (const float*)d_in[5];
    float*       out    = (float*)d_out;

    const size_t support_bytes = (size_t)N_NODES * OUT_SIZE * sizeof(float);   // 12.8 MB
    const size_t cnt_bytes     = (size_t)N_NODES * sizeof(int);                // 0.2 MB
    const size_t pay_bytes     = (size_t)N_NODES * BIN_CAP * sizeof(unsigned); // 12.8 MB

    float*    support = (float*)d_ws;
    int*      cnt     = (int*)((char*)d_ws + support_bytes);
    unsigned* pay     = (unsigned*)((char*)d_ws + support_bytes + cnt_bytes);
    int*      q       = (int*)((char*)d_ws + support_bytes + cnt_bytes + pay_bytes);

    if (ws_size >= support_bytes + cnt_bytes + pay_bytes + 1024) {
        int occ = 0;
        if (hipOccupancyMaxActiveBlocksPerMultiprocessor(&occ, gcn_coop, 256, 0)
                == hipSuccess && occ > 0) {
            if (occ > 4) occ = 4;
            int nblocks = occ * 256;            // 256 CUs on MI355X
            void* args[] = {(void*)&x, (void*)&weight, (void*)&rows, (void*)&cols,
                            (void*)&vals, (void*)&bias, (void*)&support, (void*)&cnt,
                            (void*)&pay, (void*)&q, (void*)&out};
            if (hipLaunchCooperativeKernel((void*)gcn_coop, dim3(nblocks), dim3(256),
                                           args, 0, stream) == hipSuccess)
                return;
        }
        hipMemsetAsync(cnt, 0, cnt_bytes, stream);
        fused_gemm_bin<<<G_GEMM + G_BIN, 256, 0, stream>>>(x, weight, support,
                                                           rows, cols, vals, cnt, pay);
        reduce_rows_pay<<<(N_NODES + 3) / 4, 256, 0, stream>>>(support, cnt, pay, bias, out);
        return;
    }

    hipMemsetAsync(cnt, 0, cnt_bytes, stream);
    fused_gemm_bin<<<G_GEMM + G_BIN, 256, 0, stream>>>(x, weight, support,
                                                       rows, cols, vals, cnt, pay);
    reduce_rows_pay<<<(N_NODES + 3) / 4, 256, 0, stream>>>(support, cnt, pay, bias, out);
}

// Round 12
// 92.311 us; speedup vs baseline: 3.4621x; 1.1276x over previous
//
#include <hip/hip_runtime.h>

#define N_NODES 50000
#define N_EDGES 800000
#define IN_SIZE 128
#define OUT_SIZE 64
#define BIN_CAP 64   // Poisson(16) => P(>=64) ~ 2e-18

#define BM 128
#define NGEMM ((N_NODES + BM - 1) / BM)      // 391 gemm tiles
#define NCH   (N_EDGES / 4)                  // 200000 int4 edge-groups
#define G_BIN ((NCH + 255) / 256)            // 782 bin blocks

typedef __attribute__((ext_vector_type(8))) short short8v;  // 8 bf16 (4 VGPRs)
typedef __attribute__((ext_vector_type(4))) float f32x4;

__device__ __forceinline__ unsigned short f2bf(float f) {    // RTNE fp32->bf16
    unsigned u = __float_as_uint(f);
    return (unsigned short)((u + 0x7fffu + ((u >> 16) & 1u)) >> 16);
}
__device__ __forceinline__ unsigned pk2(float a, float b) {  // pack 2 bf16
    return (unsigned)f2bf(a) | ((unsigned)f2bf(b) << 16);
}
// pay entry: low 16 = col, high 16 = bf16(val). unpack val = bits & 0xFFFF0000.
__device__ __forceinline__ unsigned pack_cv(int c, float v) {
    return (unsigned)c | ((unsigned)f2bf(v) << 16);
}

// =========================================================================
// Fused kernel (non-coop this round, for TRUSTWORTHY per-dispatch counters):
// blocks [0, NGEMM): MFMA bf16 gemm tile (R9/R10-verified fragment layout).
// blocks [NGEMM, NGEMM+G_BIN): bin chunk with 4-byte packed payload.
// Purpose: isolate MFMA gemm cost outside the coop kernel — R10's 2.6x
// regression was MFMA-inside-coop and never attributed.
// =========================================================================
__global__ __launch_bounds__(256) void fused_mfma_bin(
        const float* __restrict__ x, const float* __restrict__ w,
        float* __restrict__ support,
        const int* __restrict__ rows, const int* __restrict__ cols,
        const float* __restrict__ vals,
        int* __restrict__ cnt, unsigned* __restrict__ pay) {
    __shared__ int4 xs4[2048];     // 32 KB: bf16 x-tile, [128 rows][256 B] swizzled
    __shared__ int  wt4[4096];     // 16 KB: bf16 w^T,   [64 cols][256 B] swizzled
    char* xb = (char*)xs4;
    char* wb = (char*)wt4;
    const int tid = threadIdx.x;

    if (blockIdx.x < NGEMM) {
        // ================= MFMA gemm tile =================
        const int row0 = blockIdx.x * BM;

        // stage x tile -> bf16 LDS, swizzle: byte ^= (row&7)<<4
        #pragma unroll
        for (int i = 0; i < 8; ++i) {
            const int s   = tid + 256 * i;    // s < 2048 (row, 16B-slot)
            const int row = s >> 4;
            const int sl  = s & 15;
            int r = row0 + row; if (r > N_NODES - 1) r = N_NODES - 1;
            const float4* xp = (const float4*)(x + (long)r * IN_SIZE + sl * 8);
            const float4 f0 = xp[0], f1 = xp[1];
            int4 pk;
            pk.x = pk2(f0.x, f0.y); pk.y = pk2(f0.z, f0.w);
            pk.z = pk2(f1.x, f1.y); pk.w = pk2(f1.z, f1.w);
            *(int4*)(xb + row * 256 + ((sl * 16) ^ ((row & 7) << 4))) = pk;
        }
        // stage w^T -> bf16 LDS (same swizzle on col)
        #pragma unroll
        for (int i = 0; i < 4; ++i) {
            const int f  = tid + 256 * i;          // f < 1024
            const int kp = f >> 4;                 // k-pair 0..63
            const int c0 = (f & 15) << 2;
            const float4 w0 = *(const float4*)(w + (2 * kp) * OUT_SIZE + c0);
            const float4 w1 = *(const float4*)(w + (2 * kp + 1) * OUT_SIZE + c0);
            const float a0[4] = {w0.x, w0.y, w0.z, w0.w};
            const float a1[4] = {w1.x, w1.y, w1.z, w1.w};
            #pragma unroll
            for (int j = 0; j < 4; ++j) {
                const int c = c0 + j;
                *(unsigned*)(wb + c * 256 + ((kp * 4) ^ ((c & 7) << 4))) =
                    pk2(a0[j], a1[j]);
            }
        }
        __syncthreads();

        // wave wv owns rows [wv*32, wv*32+32) x all 64 cols
        const int l   = tid & 63;
        const int wv  = tid >> 6;
        const int rb  = wv * 32;
        const int lm  = l & 15;
        const int swz = (l & 7) << 4;
        f32x4 acc[2][4];
        #pragma unroll
        for (int a16 = 0; a16 < 2; ++a16)
            #pragma unroll
            for (int nb = 0; nb < 4; ++nb)
                acc[a16][nb] = (f32x4){0.f, 0.f, 0.f, 0.f};

        #pragma unroll
        for (int kk = 0; kk < 4; ++kk) {
            const int ko = ((kk << 6) + ((l >> 4) << 4)) ^ swz;
            const short8v a0 = *(const short8v*)(xb + (rb + lm) * 256 + ko);
            const short8v a1 = *(const short8v*)(xb + (rb + 16 + lm) * 256 + ko);
            const short8v b0 = *(const short8v*)(wb + lm * 256 + ko);
            const short8v b1 = *(const short8v*)(wb + (16 + lm) * 256 + ko);
            const short8v b2 = *(const short8v*)(wb + (32 + lm) * 256 + ko);
            const short8v b3 = *(const short8v*)(wb + (48 + lm) * 256 + ko);
            acc[0][0] = __builtin_amdgcn_mfma_f32_16x16x32_bf16(a0, b0, acc[0][0], 0, 0, 0);
            acc[0][1] = __builtin_amdgcn_mfma_f32_16x16x32_bf16(a0, b1, acc[0][1], 0, 0, 0);
            acc[0][2] = __builtin_amdgcn_mfma_f32_16x16x32_bf16(a0, b2, acc[0][2], 0, 0, 0);
            acc[0][3] = __builtin_amdgcn_mfma_f32_16x16x32_bf16(a0, b3, acc[0][3], 0, 0, 0);
            acc[1][0] = __builtin_amdgcn_mfma_f32_16x16x32_bf16(a1, b0, acc[1][0], 0, 0, 0);
            acc[1][1] = __builtin_amdgcn_mfma_f32_16x16x32_bf16(a1, b1, acc[1][1], 0, 0, 0);
            acc[1][2] = __builtin_amdgcn_mfma_f32_16x16x32_bf16(a1, b2, acc[1][2], 0, 0, 0);
            acc[1][3] = __builtin_amdgcn_mfma_f32_16x16x32_bf16(a1, b3, acc[1][3], 0, 0, 0);
        }

        // C/D layout (m89-verified): col = lane&15, row = (lane>>4)*4 + reg
        const int rr = (l >> 4) << 2;
        #pragma unroll
        for (int a16 = 0; a16 < 2; ++a16) {
            #pragma unroll
            for (int r4 = 0; r4 < 4; ++r4) {
                const int grow = row0 + rb + a16 * 16 + rr + r4;
                if (grow < N_NODES) {
                    #pragma unroll
                    for (int nb = 0; nb < 4; ++nb)
                        support[(long)grow * OUT_SIZE + nb * 16 + lm] = acc[a16][nb][r4];
                }
            }
        }
    } else {
        // ================= bin chunk (4-byte packed payload) =================
        const int i = (blockIdx.x - NGEMM) * 256 + tid;
        if (i < NCH) {
            const int4   r4 = ((const int4*)rows)[i];
            const int4   c4 = ((const int4*)cols)[i];
            const float4 v4 = ((const float4*)vals)[i];
            int s;
            s = atomicAdd(&cnt[r4.x], 1); if (s < BIN_CAP) pay[r4.x * BIN_CAP + s] = pack_cv(c4.x, v4.x);
            s = atomicAdd(&cnt[r4.y], 1); if (s < BIN_CAP) pay[r4.y * BIN_CAP + s] = pack_cv(c4.y, v4.y);
            s = atomicAdd(&cnt[r4.z], 1); if (s < BIN_CAP) pay[r4.z * BIN_CAP + s] = pack_cv(c4.z, v4.z);
            s = atomicAdd(&cnt[r4.w], 1); if (s < BIN_CAP) pay[r4.w * BIN_CAP + s] = pack_cv(c4.w, v4.w);
        }
    }
}

// =========================================================================
// Per-row gather-reduce (4-byte pay), ILP-pipelined 8-deep.
// =========================================================================
__global__ __launch_bounds__(256) void reduce_rows_pay(const float* __restrict__ support,
                                                       const int* __restrict__ cnt,
                                                       const unsigned* __restrict__ pay,
                                                       const float* __restrict__ bias,
                                                       float* __restrict__ out) {
    const int tid  = threadIdx.x;
    const int lane = tid & 63;
    const int row  = blockIdx.x * 4 + (tid >> 6);
    if (row >= N_NODES) return;
    const int n = min(cnt[row], BIN_CAP);
    unsigned p = 0;
    if (lane < n) p = pay[(long)row * BIN_CAP + lane];   // coalesced 256B/wave
    float acc = bias[lane];
    int k = 0;
    for (; k + 8 <= n; k += 8) {
        float g[8], v[8];
        #pragma unroll
        for (int j = 0; j < 8; ++j) {
            const unsigned pk = (unsigned)__shfl((int)p, k + j, 64);
            v[j] = __uint_as_float(pk & 0xFFFF0000u);
            g[j] = support[(long)(pk & 0xFFFFu) * OUT_SIZE + lane];
        }
        #pragma unroll
        for (int j = 0; j < 8; ++j) acc += g[j] * v[j];
    }
    for (; k < n; ++k) {
        const unsigned pk = (unsigned)__shfl((int)p, k, 64);
        acc += support[(long)(pk & 0xFFFFu) * OUT_SIZE + lane]
               * __uint_as_float(pk & 0xFFFF0000u);
    }
    out[(long)row * OUT_SIZE + lane] = acc;
}

// =========================================================================
extern "C" void kernel_launch(void* const* d_in, const int* in_sizes, int n_in,
                              void* d_out, int out_size, void* d_ws, size_t ws_size,
                              hipStream_t stream) {
    const float* x      = (const float*)d_in[0];
    const int*   rows   = (const int*)d_in[1];
    const int*   cols   = (const int*)d_in[2];
    const float* vals   = (const float*)d_in[3];
    const float* weight = (const float*)d_in[4];
    const float* bias   = (const float*)d_in[5];
    float*       out    = (float*)d_out;

    const size_t support_bytes = (size_t)N_NODES * OUT_SIZE * sizeof(float);   // 12.8 MB
    const size_t cnt_bytes     = (size_t)N_NODES * sizeof(int);                // 0.2 MB

    float*    support = (float*)d_ws;
    int*      cnt     = (int*)((char*)d_ws + support_bytes);
    unsigned* pay     = (unsigned*)((char*)d_ws + support_bytes + cnt_bytes);

    hipMemsetAsync(cnt, 0, cnt_bytes, stream);
    fused_mfma_bin<<<NGEMM + G_BIN, 256, 0, stream>>>(x, weight, support,
                                                      rows, cols, vals, cnt, pay);
    reduce_rows_pay<<<(N_NODES + 3) / 4, 256, 0, stream>>>(support, cnt, pay, bias, out);
}